// Round 8
// baseline (100.053 us; speedup 1.0000x reference)
//
#include <hip/hip_runtime.h>
#include <hip/hip_bf16.h>

// FastGRNN 2-layer (SRNN2). T=2048, B=256, D=32, H0=H1=64, O=35, brick=32.
// Round 8: BARRIER-FREE single-wave blocks. Each wave owns a full 16-seq x
// 64-unit recurrence tile; h is exchanged via LDS *within* the wave (program
// order + lgkmcnt, no s_barrier at all). Eliminates 4x redundant x-pack and
// all inter-wave barrier skew (l0 was VALU-issue-bound; l1 barrier-bound).
// LDS swizzle X(s) = ((s&7)<<4)^((s&8)<<2): b16 h-writes 2 lanes/bank (free),
// b128 A-frag reads evenly spread.
// l0: 1024 blocks x 64 thr, 32 steps, 12 MFMA/step (xW K=32 + hU K=64).
// l1: 16 blocks x 64 thr, 64 steps, 16 MFMA/step (xW K=64 + hU K=64),
//     fused output projection.

#define NB    64
#define BS    32
#define BATCH 256
#define D0    32
#define H     64
#define OUTD  35

typedef short  bf8   __attribute__((ext_vector_type(8)));
typedef float  f32x4 __attribute__((ext_vector_type(4)));

__device__ __forceinline__ float rcp_fast(float x) {
    return __builtin_amdgcn_rcpf(x);
}
__device__ __forceinline__ float sigm(float x) {
    return rcp_fast(1.0f + __expf(-x));
}
// tanh(x) = 2*sigm(2x)-1 : 5 VALU, NaN-free
__device__ __forceinline__ float tanh_fast(float x) {
    float q = rcp_fast(1.0f + __expf(-2.0f * x));
    return fmaf(2.0f, q, -1.0f);
}
__device__ __forceinline__ short f2bf(float f) {   // init-path only
    __hip_bfloat16 b = __float2bfloat16(f);
    return __builtin_bit_cast(short, b);
}
// packed pair -> v_cvt_pk_bf16_f32 (lo in bits[15:0])
__device__ __forceinline__ unsigned pk2bf(float lo, float hi) {
    __hip_bfloat162 h2 = __float22bfloat162_rn(make_float2(lo, hi));
    unsigned r;
    __builtin_memcpy(&r, &h2, 4);
    return r;
}

union U4BF8 { unsigned u[4]; bf8 v; };

// byte swizzle within a 128-B h row; 16-aligned so b128 reads stay aligned
__device__ __forceinline__ int swz_x(int s) {
    return ((s & 7) << 4) ^ ((s & 8) << 2);
}

__global__ __launch_bounds__(64, 2) void l0_kernel(
    const float* __restrict__ x,     // [2048][256][32]
    const float* __restrict__ W,     // [32][64]
    const float* __restrict__ U,     // [64][64]
    const float* __restrict__ bg,
    const float* __restrict__ bu,
    const float* __restrict__ zeta,
    const float* __restrict__ nu,
    float* __restrict__ last0)       // [64*256][64]
{
    __shared__ unsigned char hb[2][16 * 128];   // bf16 h, swizzled rows

    const int lane = threadIdx.x;   // 0..63
    const int l15  = lane & 15;
    const int lg   = lane >> 4;

    const int brick     = blockIdx.x >> 4;
    const int batchbase = (blockIdx.x & 15) << 4;

    // zero hb[0]: 2 KB / 64 lanes = 32 B each (in-wave, no barrier needed)
    *reinterpret_cast<float4*>(&hb[0][lane * 32])      = make_float4(0.f, 0.f, 0.f, 0.f);
    *reinterpret_cast<float4*>(&hb[0][lane * 32 + 16]) = make_float4(0.f, 0.f, 0.f, 0.f);

    // weight frags: one wave owns all 4 unit-tiles
    bf8 Wb[4], Ub0[4], Ub1[4];
#pragma unroll
    for (int T = 0; T < 4; ++T) {
        const int uc = 16 * T + l15;
#pragma unroll
        for (int j = 0; j < 8; ++j) {
            Wb[T][j]  = f2bf(W[(8 * lg + j) * H + uc]);
            Ub0[T][j] = f2bf(U[(8 * lg + j) * H + uc]);
            Ub1[T][j] = f2bf(U[(32 + 8 * lg + j) * H + uc]);
        }
    }
    float bgc[4], buc[4];
#pragma unroll
    for (int T = 0; T < 4; ++T) { bgc[T] = bg[16 * T + l15]; buc[T] = bu[16 * T + l15]; }

    const float zs  = sigm(zeta[0]);
    const float ns  = sigm(nu[0]);
    const float zns = zs + ns;

    float hc[4][4];   // [T][r]: h[seq=4lg+r][unit=16T+l15]
#pragma unroll
    for (int T = 0; T < 4; ++T)
#pragma unroll
        for (int r = 0; r < 4; ++r) hc[T][r] = 0.f;

    const float* xbase = x + ((size_t)(brick * BS) * BATCH + batchbase + l15) * D0 + 8 * lg;
    const size_t xstep = (size_t)BATCH * D0;

    float4 xa0 = reinterpret_cast<const float4*>(xbase)[0];
    float4 xa1 = reinterpret_cast<const float4*>(xbase)[1];
    float4 xn0 = reinterpret_cast<const float4*>(xbase + xstep)[0];
    float4 xn1 = reinterpret_cast<const float4*>(xbase + xstep)[1];

    const int rswz = swz_x(l15);   // read-row swizzle (row = l15)

    int cur = 0;
#pragma unroll 1
    for (int t = 0; t < BS; ++t) {
        const int tp = (t + 2 < BS) ? (t + 2) : (BS - 1);
        float4 p0 = reinterpret_cast<const float4*>(xbase + (size_t)tp * xstep)[0];
        float4 p1 = reinterpret_cast<const float4*>(xbase + (size_t)tp * xstep)[1];

        U4BF8 xp;
        xp.u[0] = pk2bf(xa0.x, xa0.y);
        xp.u[1] = pk2bf(xa0.z, xa0.w);
        xp.u[2] = pk2bf(xa1.x, xa1.y);
        xp.u[3] = pk2bf(xa1.z, xa1.w);

        // h A-frags (row l15, k = units)
        const unsigned char* hr = &hb[cur][l15 * 128];
        bf8 ha0 = *reinterpret_cast<const bf8*>(hr + ((16 * lg) ^ rswz));
        bf8 ha1 = *reinterpret_cast<const bf8*>(hr + ((64 + 16 * lg) ^ rswz));

        f32x4 acc[4];
#pragma unroll
        for (int T = 0; T < 4; ++T) {
            f32x4 a = {0.f, 0.f, 0.f, 0.f};
            a = __builtin_amdgcn_mfma_f32_16x16x32_bf16(xp.v, Wb[T], a, 0, 0, 0);
            a = __builtin_amdgcn_mfma_f32_16x16x32_bf16(ha0, Ub0[T], a, 0, 0, 0);
            a = __builtin_amdgcn_mfma_f32_16x16x32_bf16(ha1, Ub1[T], a, 0, 0, 0);
            acc[T] = a;
        }

        // activation + h write (in-wave LDS, no barrier)
        unsigned char* wb = &hb[cur ^ 1][0];
#pragma unroll
        for (int T = 0; T < 4; ++T) {
#pragma unroll
            for (int r = 0; r < 4; ++r) {
                float z = sigm(acc[T][r] + bgc[T]);
                float c = tanh_fast(acc[T][r] + buc[T]);
                float w = fmaf(-zs, z, zns);
                hc[T][r] = fmaf(z, hc[T][r], w * c);
            }
            unsigned pkA = pk2bf(hc[T][0], hc[T][1]);
            unsigned pkB = pk2bf(hc[T][2], hc[T][3]);
            {
                int s0 = 4 * lg + 0;
                int s1 = 4 * lg + 1;
                int s2 = 4 * lg + 2;
                int s3 = 4 * lg + 3;
                int cb = 32 * T + 2 * l15;
                *reinterpret_cast<unsigned short*>(wb + s0 * 128 + (cb ^ swz_x(s0))) = (unsigned short)pkA;
                *reinterpret_cast<unsigned short*>(wb + s1 * 128 + (cb ^ swz_x(s1))) = (unsigned short)(pkA >> 16);
                *reinterpret_cast<unsigned short*>(wb + s2 * 128 + (cb ^ swz_x(s2))) = (unsigned short)pkB;
                *reinterpret_cast<unsigned short*>(wb + s3 * 128 + (cb ^ swz_x(s3))) = (unsigned short)(pkB >> 16);
            }
        }
        cur ^= 1;
        xa0 = xn0; xa1 = xn1;
        xn0 = p0;  xn1 = p1;
    }

    // last hidden state (fp32), coalesced over l15
    {
        float* op = last0 + ((size_t)(brick * BATCH + batchbase)) * H;
#pragma unroll
        for (int T = 0; T < 4; ++T)
#pragma unroll
            for (int r = 0; r < 4; ++r)
                op[(size_t)(4 * lg + r) * H + 16 * T + l15] = hc[T][r];
    }
}

// Layer 1 + projection: 16 blocks x 64 thr (1 wave), 16 batches each, 64 steps.
__global__ __launch_bounds__(64, 2) void l1_kernel(
    const float* __restrict__ last0,  // [64][256][64]
    const float* __restrict__ W,      // [64][64]
    const float* __restrict__ U,      // [64][64]
    const float* __restrict__ bg,
    const float* __restrict__ bu,
    const float* __restrict__ zeta,
    const float* __restrict__ nu,
    const float* __restrict__ Wout,   // [64][35]
    const float* __restrict__ Bout,   // [35]
    float* __restrict__ out)          // [256][35]
{
    __shared__ unsigned char hb[2][16 * 128];
    __shared__ float hsf[16][H];

    const int lane = threadIdx.x;
    const int l15  = lane & 15;
    const int lg   = lane >> 4;

    const int batchbase = blockIdx.x << 4;

    *reinterpret_cast<float4*>(&hb[0][lane * 32])      = make_float4(0.f, 0.f, 0.f, 0.f);
    *reinterpret_cast<float4*>(&hb[0][lane * 32 + 16]) = make_float4(0.f, 0.f, 0.f, 0.f);

    bf8 Wb0[4], Wb1[4], Ub0[4], Ub1[4];
#pragma unroll
    for (int T = 0; T < 4; ++T) {
        const int uc = 16 * T + l15;
#pragma unroll
        for (int j = 0; j < 8; ++j) {
            Wb0[T][j] = f2bf(W[(8 * lg + j) * H + uc]);
            Wb1[T][j] = f2bf(W[(32 + 8 * lg + j) * H + uc]);
            Ub0[T][j] = f2bf(U[(8 * lg + j) * H + uc]);
            Ub1[T][j] = f2bf(U[(32 + 8 * lg + j) * H + uc]);
        }
    }
    float bgc[4], buc[4];
#pragma unroll
    for (int T = 0; T < 4; ++T) { bgc[T] = bg[16 * T + l15]; buc[T] = bu[16 * T + l15]; }

    const float zs  = sigm(zeta[0]);
    const float ns  = sigm(nu[0]);
    const float zns = zs + ns;

    float hc[4][4];
#pragma unroll
    for (int T = 0; T < 4; ++T)
#pragma unroll
        for (int r = 0; r < 4; ++r) hc[T][r] = 0.f;

    const float* abase = last0 + ((size_t)(batchbase + l15)) * H + 8 * lg;
    const size_t astep = (size_t)BATCH * H;

    float4 cA0 = reinterpret_cast<const float4*>(abase)[0];
    float4 cA1 = reinterpret_cast<const float4*>(abase)[1];
    float4 cA2 = reinterpret_cast<const float4*>(abase + 32)[0];
    float4 cA3 = reinterpret_cast<const float4*>(abase + 32)[1];
    float4 nA0 = reinterpret_cast<const float4*>(abase + astep)[0];
    float4 nA1 = reinterpret_cast<const float4*>(abase + astep)[1];
    float4 nA2 = reinterpret_cast<const float4*>(abase + astep + 32)[0];
    float4 nA3 = reinterpret_cast<const float4*>(abase + astep + 32)[1];

    const int rswz = swz_x(l15);

    int cur = 0;
#pragma unroll 1
    for (int t = 0; t < NB; ++t) {
        const int tp = (t + 2 < NB) ? (t + 2) : (NB - 1);
        float4 p0 = reinterpret_cast<const float4*>(abase + (size_t)tp * astep)[0];
        float4 p1 = reinterpret_cast<const float4*>(abase + (size_t)tp * astep)[1];
        float4 p2 = reinterpret_cast<const float4*>(abase + (size_t)tp * astep + 32)[0];
        float4 p3 = reinterpret_cast<const float4*>(abase + (size_t)tp * astep + 32)[1];

        U4BF8 a0, a1;
        a0.u[0] = pk2bf(cA0.x, cA0.y);
        a0.u[1] = pk2bf(cA0.z, cA0.w);
        a0.u[2] = pk2bf(cA1.x, cA1.y);
        a0.u[3] = pk2bf(cA1.z, cA1.w);
        a1.u[0] = pk2bf(cA2.x, cA2.y);
        a1.u[1] = pk2bf(cA2.z, cA2.w);
        a1.u[2] = pk2bf(cA3.x, cA3.y);
        a1.u[3] = pk2bf(cA3.z, cA3.w);

        const unsigned char* hr = &hb[cur][l15 * 128];
        bf8 ha0 = *reinterpret_cast<const bf8*>(hr + ((16 * lg) ^ rswz));
        bf8 ha1 = *reinterpret_cast<const bf8*>(hr + ((64 + 16 * lg) ^ rswz));

        f32x4 acc[4];
#pragma unroll
        for (int T = 0; T < 4; ++T) {
            f32x4 a = {0.f, 0.f, 0.f, 0.f};
            a = __builtin_amdgcn_mfma_f32_16x16x32_bf16(a0.v, Wb0[T], a, 0, 0, 0);
            a = __builtin_amdgcn_mfma_f32_16x16x32_bf16(a1.v, Wb1[T], a, 0, 0, 0);
            a = __builtin_amdgcn_mfma_f32_16x16x32_bf16(ha0, Ub0[T], a, 0, 0, 0);
            a = __builtin_amdgcn_mfma_f32_16x16x32_bf16(ha1, Ub1[T], a, 0, 0, 0);
            acc[T] = a;
        }

        unsigned char* wb = &hb[cur ^ 1][0];
#pragma unroll
        for (int T = 0; T < 4; ++T) {
#pragma unroll
            for (int r = 0; r < 4; ++r) {
                float z = sigm(acc[T][r] + bgc[T]);
                float c = tanh_fast(acc[T][r] + buc[T]);
                float w = fmaf(-zs, z, zns);
                hc[T][r] = fmaf(z, hc[T][r], w * c);
            }
            unsigned pkA = pk2bf(hc[T][0], hc[T][1]);
            unsigned pkB = pk2bf(hc[T][2], hc[T][3]);
            {
                int s0 = 4 * lg + 0;
                int s1 = 4 * lg + 1;
                int s2 = 4 * lg + 2;
                int s3 = 4 * lg + 3;
                int cb = 32 * T + 2 * l15;
                *reinterpret_cast<unsigned short*>(wb + s0 * 128 + (cb ^ swz_x(s0))) = (unsigned short)pkA;
                *reinterpret_cast<unsigned short*>(wb + s1 * 128 + (cb ^ swz_x(s1))) = (unsigned short)(pkA >> 16);
                *reinterpret_cast<unsigned short*>(wb + s2 * 128 + (cb ^ swz_x(s2))) = (unsigned short)pkB;
                *reinterpret_cast<unsigned short*>(wb + s3 * 128 + (cb ^ swz_x(s3))) = (unsigned short)(pkB >> 16);
            }
        }
        cur ^= 1;
        cA0 = nA0; cA1 = nA1; cA2 = nA2; cA3 = nA3;
        nA0 = p0;  nA1 = p1;  nA2 = p2;  nA3 = p3;
    }

    // stage final h (fp32) then fused projection (in-wave ordering, no barrier)
#pragma unroll
    for (int T = 0; T < 4; ++T)
#pragma unroll
        for (int r = 0; r < 4; ++r)
            hsf[4 * lg + r][16 * T + l15] = hc[T][r];

    for (int p = lane; p < 16 * OUTD; p += 64) {
        int s = p / OUTD;
        int o = p - s * OUTD;
        float a = Bout[o];
#pragma unroll
        for (int u = 0; u < H; ++u) a = fmaf(hsf[s][u], Wout[u * OUTD + o], a);
        out[(size_t)(batchbase + s) * OUTD + o] = a;
    }
}

extern "C" void kernel_launch(void* const* d_in, const int* in_sizes, int n_in,
                              void* d_out, int out_size, void* d_ws, size_t ws_size,
                              hipStream_t stream) {
    const float* x    = (const float*)d_in[0];
    const float* W0   = (const float*)d_in[2];
    const float* U0   = (const float*)d_in[3];
    const float* bg0  = (const float*)d_in[4];
    const float* bu0  = (const float*)d_in[5];
    const float* z0   = (const float*)d_in[6];
    const float* n0   = (const float*)d_in[7];
    const float* W1   = (const float*)d_in[8];
    const float* U1   = (const float*)d_in[9];
    const float* bg1  = (const float*)d_in[10];
    const float* bu1  = (const float*)d_in[11];
    const float* z1   = (const float*)d_in[12];
    const float* n1   = (const float*)d_in[13];
    const float* Wout = (const float*)d_in[14];
    const float* Bout = (const float*)d_in[15];
    float* out = (float*)d_out;

    float* last0 = (float*)d_ws;   // 4 MB scratch

    l0_kernel<<<1024, 64, 0, stream>>>(x, W0, U0, bg0, bu0, z0, n0, last0);
    l1_kernel<<<16, 64, 0, stream>>>(last0, W1, U1, bg1, bu1, z1, n1, Wout, Bout, out);
}

// Round 10
// 82.374 us; speedup vs baseline: 1.2146x; 1.2146x over previous
//
#include <hip/hip_runtime.h>
#include <hip/hip_bf16.h>

// FastGRNN 2-layer (SRNN2). T=2048, B=256, D=32, H0=H1=64, O=35, brick=32.
// Round 10 (= round 9 + type fix): TRANSPOSED register-closed recurrence.
//   Compute P^T = U^T h^T + W^T x^T with mfma_f32_16x16x16f16 (K=16).
//   C/D layout (col=lane&15,row=4*(lane>>4)+reg) == B-frag k-layout (k=4lg+j),
//   so activation output packs (cvt_pkrtz pairs) ARE next step's B-frags:
//   zero LDS, zero barriers, zero cross-lane ops in the l0 recurrence.
//   Activation: b=a^2*Ku (shares one exp) + combined rcp((1+a)(1+b)) -> both
//   inverses: 2 transcendentals/output instead of 4. Clamp pre to +-12.
// l0: 1024 blocks x 64 thr (1 wave, 16 seqs, all 64 units). 24 MFMA/step.
// l1: 16 blocks x 256 thr (4 waves; wave T owns unit-tile T). h exchanged as
//   uint2 via tiny double-buffered LDS + lgkm-only barrier. last0 passed as
//   packed f16 uint2 [t][chunk][lg][b] (2 MB, coalesced, zero-cvt B-frags).

#define NB    64
#define BS    32
#define BATCH 256
#define D0    32
#define H     64
#define OUTD  35
#define LOG2E 1.44269504088896340736f

typedef _Float16 h4    __attribute__((ext_vector_type(4)));   // MFMA operand view
typedef __fp16   hf2   __attribute__((ext_vector_type(2)));   // cvt_pkrtz return type
typedef float    f32x4 __attribute__((ext_vector_type(4)));

union HB { h4 v; hf2 h[2]; unsigned u[2]; };

__device__ __forceinline__ float rcp_fast(float x) {
    return __builtin_amdgcn_rcpf(x);
}
__device__ __forceinline__ float sigm(float x) {   // init-path only
    return rcp_fast(1.0f + __expf(-x));
}
// LDS-only barrier: drains ds ops, leaves global loads in flight (round-7 proven)
__device__ __forceinline__ void lds_barrier() {
    asm volatile("s_waitcnt lgkmcnt(0)\n\ts_barrier" ::: "memory");
}

// fused activation+update for one element; 2 transcendentals (exp2, rcp)
// a = exp(-(t+bg)) via exp2(fma(t,-log2e,bgp)), b = a*a*Ku = exp(-2(t+bu))
// z = 1/(1+a), c = tanh = 2/(1+b)-1 ; one rcp of (1+a)(1+b) gives both.
__device__ __forceinline__ void act_update(float pre, float bgp, float Ku,
                                           float zs, float zns, float& hcr) {
    float t  = fminf(fmaxf(pre, -12.f), 12.f);
    float a  = exp2f(fmaf(t, -LOG2E, bgp));
    float b  = a * a * Ku;
    float da = 1.f + a, db = 1.f + b;
    float rr = rcp_fast(da * db);
    float z  = rr * db;           // 1/(1+a)
    float ib = rr * da;           // 1/(1+b)
    float c  = fmaf(2.f, ib, -1.f);
    float w  = fmaf(-zs, z, zns); // zs*(1-z)+ns
    hcr = fmaf(z, hcr, w * c);
}

// ---------------- Layer 0: 1 wave, 16 seqs x 64 units, no LDS ---------------
__global__ __launch_bounds__(64, 2) void l0_kernel(
    const float* __restrict__ x,     // [2048][256][32]
    const float* __restrict__ W,     // [32][64]
    const float* __restrict__ U,     // [64][64]
    const float* __restrict__ bg,
    const float* __restrict__ bu,
    const float* __restrict__ zeta,
    const float* __restrict__ nu,
    unsigned* __restrict__ last0pk)  // [64][4][4][256] uint2 (packed f16)
{
    const int lane = threadIdx.x;
    const int l15  = lane & 15;
    const int lg   = lane >> 4;

    const int brick     = blockIdx.x >> 4;
    const int batchbase = (blockIdx.x & 15) << 4;

    // A-frags (loaded once): Wt[T][c] = W^T rows u=16T+l15, k=16c+4lg+j
    h4 Wt[4][2], Ut[4][4];
#pragma unroll
    for (int T = 0; T < 4; ++T) {
        const int u = 16 * T + l15;
#pragma unroll
        for (int c = 0; c < 2; ++c)
#pragma unroll
            for (int j = 0; j < 4; ++j)
                Wt[T][c][j] = (_Float16)W[(16 * c + 4 * lg + j) * H + u];
#pragma unroll
        for (int c = 0; c < 4; ++c)
#pragma unroll
            for (int j = 0; j < 4; ++j)
                Ut[T][c][j] = (_Float16)U[(16 * c + 4 * lg + j) * H + u];
    }

    float bgp[4][4], Ku[4][4];
#pragma unroll
    for (int T = 0; T < 4; ++T)
#pragma unroll
        for (int r = 0; r < 4; ++r) {
            int u = 16 * T + 4 * lg + r;
            float g = bg[u], q = bu[u];
            bgp[T][r] = -LOG2E * g;
            Ku[T][r]  = exp2f(2.f * LOG2E * (g - q));
        }

    const float zs  = sigm(zeta[0]);
    const float ns  = sigm(nu[0]);
    const float zns = zs + ns;

    float hc[4][4];
#pragma unroll
    for (int T = 0; T < 4; ++T)
#pragma unroll
        for (int r = 0; r < 4; ++r) hc[T][r] = 0.f;

    HB hbf[4];
#pragma unroll
    for (int c = 0; c < 4; ++c) { hbf[c].u[0] = 0; hbf[c].u[1] = 0; }

    // x B-frag source: lane reads x[batchbase+l15][16c+4lg .. +3], c=0,1
    const float* xb = x + ((size_t)(brick * BS) * BATCH + batchbase + l15) * D0 + 4 * lg;
    const size_t xstep = (size_t)BATCH * D0;

    float4 c0 = reinterpret_cast<const float4*>(xb)[0];
    float4 c1 = reinterpret_cast<const float4*>(xb + 16)[0];
    float4 n0 = reinterpret_cast<const float4*>(xb + xstep)[0];
    float4 n1 = reinterpret_cast<const float4*>(xb + xstep + 16)[0];

#pragma unroll 1
    for (int t = 0; t < BS; ++t) {
        const int tp = (t + 2 < BS) ? (t + 2) : (BS - 1);
        float4 p0 = reinterpret_cast<const float4*>(xb + (size_t)tp * xstep)[0];
        float4 p1 = reinterpret_cast<const float4*>(xb + (size_t)tp * xstep + 16)[0];

        HB xf0, xf1;
        xf0.h[0] = __builtin_amdgcn_cvt_pkrtz(c0.x, c0.y);
        xf0.h[1] = __builtin_amdgcn_cvt_pkrtz(c0.z, c0.w);
        xf1.h[0] = __builtin_amdgcn_cvt_pkrtz(c1.x, c1.y);
        xf1.h[1] = __builtin_amdgcn_cvt_pkrtz(c1.z, c1.w);

        f32x4 acc[4];
#pragma unroll
        for (int T = 0; T < 4; ++T) {
            f32x4 a = {0.f, 0.f, 0.f, 0.f};
            a = __builtin_amdgcn_mfma_f32_16x16x16f16(Wt[T][0], xf0.v, a, 0, 0, 0);
            a = __builtin_amdgcn_mfma_f32_16x16x16f16(Wt[T][1], xf1.v, a, 0, 0, 0);
#pragma unroll
            for (int c = 0; c < 4; ++c)
                a = __builtin_amdgcn_mfma_f32_16x16x16f16(Ut[T][c], hbf[c].v, a, 0, 0, 0);
            acc[T] = a;
        }

#pragma unroll
        for (int T = 0; T < 4; ++T)
#pragma unroll
            for (int r = 0; r < 4; ++r)
                act_update(acc[T][r], bgp[T][r], Ku[T][r], zs, zns, hc[T][r]);

        // pack: next step's B-frags, in-register (the transposed-closure trick)
#pragma unroll
        for (int c = 0; c < 4; ++c) {
            hbf[c].h[0] = __builtin_amdgcn_cvt_pkrtz(hc[c][0], hc[c][1]);
            hbf[c].h[1] = __builtin_amdgcn_cvt_pkrtz(hc[c][2], hc[c][3]);
        }

        c0 = n0; c1 = n1;
        n0 = p0; n1 = p1;
    }

    // store packed f16 h_final: last0pk[brick][T][lg][b] as uint2
#pragma unroll
    for (int T = 0; T < 4; ++T) {
        size_t idx = ((((size_t)brick * 4 + T) * 4 + lg) * 256 + batchbase + l15) * 2;
        *reinterpret_cast<uint2*>(&last0pk[idx]) = make_uint2(hbf[T].u[0], hbf[T].u[1]);
    }
}

// ------- Layer 1: 4 waves, wave T owns unit-tile T; uint2 LDS h-exchange -----
__global__ __launch_bounds__(256, 2) void l1_kernel(
    const unsigned* __restrict__ last0pk,  // [64][4][4][256] uint2
    const float* __restrict__ W,           // [64][64]
    const float* __restrict__ U,           // [64][64]
    const float* __restrict__ bg,
    const float* __restrict__ bu,
    const float* __restrict__ zeta,
    const float* __restrict__ nu,
    const float* __restrict__ Wout,        // [64][35]
    const float* __restrict__ Bout,        // [35]
    float* __restrict__ out)               // [256][35]
{
    __shared__ unsigned hx[2][4][4][16][2];   // [buf][chunk][lg][s][dword] 4KB
    __shared__ float hsf[16][H];

    const int tid  = threadIdx.x;
    const int lane = tid & 63;
    const int T    = __builtin_amdgcn_readfirstlane(tid >> 6);   // unit tile
    const int l15  = lane & 15;
    const int lg   = lane >> 4;

    const int batchbase = blockIdx.x << 4;

    // zero h LDS (1024 dwords)
    for (int i = tid; i < 1024; i += 256) (&hx[0][0][0][0][0])[i] = 0;

    h4 Wt[4], Ut[4];
#pragma unroll
    for (int c = 0; c < 4; ++c) {
        const int u = 16 * T + l15;
#pragma unroll
        for (int j = 0; j < 4; ++j) {
            Wt[c][j] = (_Float16)W[(16 * c + 4 * lg + j) * H + u];
            Ut[c][j] = (_Float16)U[(16 * c + 4 * lg + j) * H + u];
        }
    }
    float bgp[4], Ku[4];
#pragma unroll
    for (int r = 0; r < 4; ++r) {
        int u = 16 * T + 4 * lg + r;
        float g = bg[u], q = bu[u];
        bgp[r] = -LOG2E * g;
        Ku[r]  = exp2f(2.f * LOG2E * (g - q));
    }

    const float zs  = sigm(zeta[0]);
    const float ns  = sigm(nu[0]);
    const float zns = zs + ns;

    float hc[4] = {0.f, 0.f, 0.f, 0.f};

    // x (=last0pk) B-frags: uint2 at [t][c][lg][batchbase+l15]
#define XIDX(t, c) (((((size_t)(t) * 4 + (c)) * 4 + lg) * 256 + batchbase + l15) * 2)
    uint2 xc[4], xn[4], xp[4];
#pragma unroll
    for (int c = 0; c < 4; ++c) {
        xc[c] = *reinterpret_cast<const uint2*>(&last0pk[XIDX(0, c)]);
        xn[c] = *reinterpret_cast<const uint2*>(&last0pk[XIDX(1, c)]);
    }

    __syncthreads();

    int buf = 0;
#pragma unroll 1
    for (int t = 0; t < NB; ++t) {
        const int tp = (t + 2 < NB) ? (t + 2) : (NB - 1);
#pragma unroll
        for (int c = 0; c < 4; ++c)
            xp[c] = *reinterpret_cast<const uint2*>(&last0pk[XIDX(tp, c)]);

        // read all 4 h chunks (own chunk was written to this buf last step)
        HB hf[4];
#pragma unroll
        for (int c = 0; c < 4; ++c) {
            uint2 v = *reinterpret_cast<const uint2*>(&hx[buf][c][lg][l15][0]);
            hf[c].u[0] = v.x; hf[c].u[1] = v.y;
        }

        // split accumulators: ax (x-part, regs ready) || ah (h-part)
        f32x4 ax = {0.f, 0.f, 0.f, 0.f};
        f32x4 ah = {0.f, 0.f, 0.f, 0.f};
#pragma unroll
        for (int c = 0; c < 4; ++c) {
            HB xv; xv.u[0] = xc[c].x; xv.u[1] = xc[c].y;
            ax = __builtin_amdgcn_mfma_f32_16x16x16f16(Wt[c], xv.v, ax, 0, 0, 0);
        }
#pragma unroll
        for (int c = 0; c < 4; ++c)
            ah = __builtin_amdgcn_mfma_f32_16x16x16f16(Ut[c], hf[c].v, ah, 0, 0, 0);

        HB ho;
#pragma unroll
        for (int r = 0; r < 4; ++r)
            act_update(ax[r] + ah[r], bgp[r], Ku[r], zs, zns, hc[r]);
        ho.h[0] = __builtin_amdgcn_cvt_pkrtz(hc[0], hc[1]);
        ho.h[1] = __builtin_amdgcn_cvt_pkrtz(hc[2], hc[3]);

        *reinterpret_cast<uint2*>(&hx[buf ^ 1][T][lg][l15][0]) = make_uint2(ho.u[0], ho.u[1]);
        lds_barrier();                 // ds drained; global prefetch in flight
        buf ^= 1;
#pragma unroll
        for (int c = 0; c < 4; ++c) { xc[c] = xn[c]; xn[c] = xp[c]; }
    }
#undef XIDX

    // stage final h, fused projection
#pragma unroll
    for (int r = 0; r < 4; ++r) hsf[l15][16 * T + 4 * lg + r] = hc[r];
    __syncthreads();

    for (int p = tid; p < 16 * OUTD; p += 256) {
        int s = p / OUTD;
        int o = p - s * OUTD;
        float a = Bout[o];
#pragma unroll
        for (int u = 0; u < H; ++u) a = fmaf(hsf[s][u], Wout[u * OUTD + o], a);
        out[(size_t)(batchbase + s) * OUTD + o] = a;
    }
}

extern "C" void kernel_launch(void* const* d_in, const int* in_sizes, int n_in,
                              void* d_out, int out_size, void* d_ws, size_t ws_size,
                              hipStream_t stream) {
    const float* x    = (const float*)d_in[0];
    const float* W0   = (const float*)d_in[2];
    const float* U0   = (const float*)d_in[3];
    const float* bg0  = (const float*)d_in[4];
    const float* bu0  = (const float*)d_in[5];
    const float* z0   = (const float*)d_in[6];
    const float* n0   = (const float*)d_in[7];
    const float* W1   = (const float*)d_in[8];
    const float* U1   = (const float*)d_in[9];
    const float* bg1  = (const float*)d_in[10];
    const float* bu1  = (const float*)d_in[11];
    const float* z1   = (const float*)d_in[12];
    const float* n1   = (const float*)d_in[13];
    const float* Wout = (const float*)d_in[14];
    const float* Bout = (const float*)d_in[15];
    float* out = (float*)d_out;

    unsigned* last0pk = (unsigned*)d_ws;   // 2 MB packed-f16 scratch

    l0_kernel<<<1024, 64, 0, stream>>>(x, W0, U0, bg0, bu0, z0, n0, last0pk);
    l1_kernel<<<16, 256, 0, stream>>>(last0pk, W1, U1, bg1, bu1, z1, n1, Wout, Bout, out);
}